// Round 3
// baseline (653.914 us; speedup 1.0000x reference)
//
#include <hip/hip_runtime.h>

#define B_ 2
#define S_ 512
#define H_ 1024
#define E_ 4
#define V_ 32000
#define T_ (B_ * S_)            // 1024 tokens
#define V4_ (V_ / 4)            // 8000 float4 per token-row
#define EXPERT_STRIDE4 ((size_t)B_ * S_ * V4_)   // 8,192,000 float4 between experts
#define OUT_PROB_OFF ((size_t)B_ * S_ * V_)      // 32,768,000 floats

// ws layout: [0..3] int max_k; [16 .. 16+16K) int sorted_idx[T][4];
//            [16+16K .. 16+32K) float sorted_prob[T][4]

__global__ void init_ws_kernel(int* maxk) { *maxk = 0; }

__global__ __launch_bounds__(256) void router_kernel(
    const float* __restrict__ emb, const float* __restrict__ noise,
    const float* __restrict__ Wr, const float* __restrict__ br,
    const float* __restrict__ Wn, const float* __restrict__ bn,
    float* __restrict__ out, int* __restrict__ maxk,
    int* __restrict__ sidx, float* __restrict__ sprob)
{
    const int wave = threadIdx.x >> 6;
    const int lane = threadIdx.x & 63;
    const int t = blockIdx.x * 4 + wave;   // one wave per token; grid = T/4

    float accr[E_] = {0.f, 0.f, 0.f, 0.f};
    float accn[E_] = {0.f, 0.f, 0.f, 0.f};
    const float* ep = emb + (size_t)t * H_;
    #pragma unroll
    for (int it = 0; it < H_ / 64; ++it) {
        const int h = lane + it * 64;
        const float ev = ep[h];
        const float4 wr = *(const float4*)(Wr + h * E_);  // row h of Wr is 4 contiguous f32
        const float4 wn = *(const float4*)(Wn + h * E_);
        accr[0] += ev * wr.x; accr[1] += ev * wr.y; accr[2] += ev * wr.z; accr[3] += ev * wr.w;
        accn[0] += ev * wn.x; accn[1] += ev * wn.y; accn[2] += ev * wn.z; accn[3] += ev * wn.w;
    }
    // wave64 butterfly reduce the 8 accumulators
    #pragma unroll
    for (int off = 32; off >= 1; off >>= 1) {
        #pragma unroll
        for (int e = 0; e < E_; ++e) {
            accr[e] += __shfl_down(accr[e], off, 64);
            accn[e] += __shfl_down(accn[e], off, 64);
        }
    }

    if (lane == 0) {
        float rl[E_], p[E_];
        #pragma unroll
        for (int e = 0; e < E_; ++e) {
            const float nx = accn[e] + bn[e];
            // softplus(x) = max(x,0) + log1p(exp(-|x|))  (jax.nn.softplus-stable)
            const float sp = fmaxf(nx, 0.f) + log1pf(expf(-fabsf(nx)));
            rl[e] = accr[e] + br[e] + noise[t * E_ + e] * sp;
        }
        const float m = fmaxf(fmaxf(rl[0], rl[1]), fmaxf(rl[2], rl[3]));
        float s = 0.f;
        #pragma unroll
        for (int e = 0; e < E_; ++e) { p[e] = expf(rl[e] - m); s += p[e]; }
        const float inv = 1.f / s;
        #pragma unroll
        for (int e = 0; e < E_; ++e) p[e] *= inv;

        // route_prob and route_prob_revised (identical) straight to d_out
        #pragma unroll
        for (int e = 0; e < E_; ++e) {
            out[OUT_PROB_OFF + (size_t)t * E_ + e]                   = p[e];
            out[OUT_PROB_OFF + (size_t)T_ * E_ + (size_t)t * E_ + e] = p[e];
        }

        // stable descending sort of 4 (matches argsort(-p) stability)
        float pr[E_]; int id[E_];
        #pragma unroll
        for (int e = 0; e < E_; ++e) { pr[e] = p[e]; id[e] = e; }
        for (int i = 1; i < E_; ++i) {
            const float pv = pr[i]; const int iv = id[i];
            int j = i - 1;
            while (j >= 0 && pr[j] < pv) { pr[j+1] = pr[j]; id[j+1] = id[j]; --j; }
            pr[j+1] = pv; id[j+1] = iv;
        }
        // mask = cum < 0.5, mask[0] forced true; cum nondecreasing -> prefix count
        float cum = pr[0];
        int k = 1;
        #pragma unroll
        for (int i = 1; i < E_; ++i) { cum += pr[i]; k += (cum < 0.5f) ? 1 : 0; }
        atomicMax(maxk, k);

        #pragma unroll
        for (int e = 0; e < E_; ++e) {
            sidx[t * E_ + e]  = id[e];
            sprob[t * E_ + e] = pr[e];
        }
    }
}

__global__ __launch_bounds__(256) void combine_kernel(
    const float4* __restrict__ logits, const int* __restrict__ maxk,
    const int* __restrict__ sidx, const float* __restrict__ sprob,
    float4* __restrict__ out)
{
    const int t = blockIdx.y;
    const int v = blockIdx.x * 256 + threadIdx.x;

    __shared__ int k_s;
    __shared__ int id_s[E_];
    __shared__ float w_s[E_];
    if (threadIdx.x == 0) {
        const int k = *maxk;
        k_s = k;
        float pr[E_]; float s = 0.f;
        #pragma unroll
        for (int j = 0; j < E_; ++j) {
            id_s[j] = sidx[t * E_ + j];
            pr[j] = (j < k) ? sprob[t * E_ + j] : 0.f;
            s += pr[j];
        }
        const float inv = 1.f / (s + 1e-6f);
        #pragma unroll
        for (int j = 0; j < E_; ++j) w_s[j] = pr[j] * inv;
    }
    __syncthreads();
    if (v >= V4_) return;

    const int k = k_s;
    const size_t tv = (size_t)t * V4_ + v;
    float4 acc = {0.f, 0.f, 0.f, 0.f};
    for (int j = 0; j < k; ++j) {          // only max_k experts have nonzero weight
        const float w = w_s[j];
        const float4 l = logits[(size_t)id_s[j] * EXPERT_STRIDE4 + tv];
        acc.x += w * l.x; acc.y += w * l.y; acc.z += w * l.z; acc.w += w * l.w;
    }
    out[tv] = acc;
}

extern "C" void kernel_launch(void* const* d_in, const int* in_sizes, int n_in,
                              void* d_out, int out_size, void* d_ws, size_t ws_size,
                              hipStream_t stream) {
    const float* emb   = (const float*)d_in[0];
    const float* logit = (const float*)d_in[1];
    const float* noise = (const float*)d_in[2];
    const float* Wr    = (const float*)d_in[3];
    const float* br    = (const float*)d_in[4];
    const float* Wn    = (const float*)d_in[5];
    const float* bn    = (const float*)d_in[6];
    float* out = (float*)d_out;

    int*   maxk  = (int*)d_ws;
    int*   sidx  = (int*)((char*)d_ws + 16);
    float* sprob = (float*)((char*)d_ws + 16 + T_ * E_ * sizeof(int));

    init_ws_kernel<<<1, 1, 0, stream>>>(maxk);
    router_kernel<<<T_ / 4, 256, 0, stream>>>(emb, noise, Wr, br, Wn, bn,
                                              out, maxk, sidx, sprob);
    dim3 cgrid((V4_ + 255) / 256, T_);
    combine_kernel<<<cgrid, 256, 0, stream>>>((const float4*)logit, maxk,
                                              sidx, sprob, (float4*)d_out);
}

// Round 7
// 652.612 us; speedup vs baseline: 1.0020x; 1.0020x over previous
//
#include <hip/hip_runtime.h>

#define B_ 2
#define S_ 512
#define H_ 1024
#define E_ 4
#define V_ 32000
#define T_ (B_ * S_)            // 1024 tokens
#define V4_ (V_ / 4)            // 8000 float4 per token-row
#define HALF4_ (V4_ / 2)        // 4000
#define EXPERT_STRIDE4 ((size_t)B_ * S_ * V4_)   // 8,192,000 float4 between experts
#define OUT_PROB_OFF ((size_t)B_ * S_ * V_)      // 32,768,000 floats

// ws layout: [0..3] int max_k; [16 .. 16+16K) int sorted_idx[T][4];
//            [16+16K .. 16+32K) float sorted_prob[T][4]

__global__ void init_ws_kernel(int* maxk) { *maxk = 0; }

__global__ __launch_bounds__(256) void router_kernel(
    const float* __restrict__ emb, const float* __restrict__ noise,
    const float* __restrict__ Wr, const float* __restrict__ br,
    const float* __restrict__ Wn, const float* __restrict__ bn,
    float* __restrict__ out, int* __restrict__ maxk,
    int* __restrict__ sidx, float* __restrict__ sprob)
{
    const int wave = threadIdx.x >> 6;
    const int lane = threadIdx.x & 63;
    const int t = blockIdx.x * 4 + wave;   // one wave per token; grid = T/4

    float accr[E_] = {0.f, 0.f, 0.f, 0.f};
    float accn[E_] = {0.f, 0.f, 0.f, 0.f};
    const float* ep = emb + (size_t)t * H_;
    #pragma unroll
    for (int it = 0; it < H_ / 64; ++it) {
        const int h = lane + it * 64;
        const float ev = ep[h];
        const float4 wr = *(const float4*)(Wr + h * E_);  // row h of Wr is 4 contiguous f32
        const float4 wn = *(const float4*)(Wn + h * E_);
        accr[0] += ev * wr.x; accr[1] += ev * wr.y; accr[2] += ev * wr.z; accr[3] += ev * wr.w;
        accn[0] += ev * wn.x; accn[1] += ev * wn.y; accn[2] += ev * wn.z; accn[3] += ev * wn.w;
    }
    // wave64 butterfly reduce the 8 accumulators
    #pragma unroll
    for (int off = 32; off >= 1; off >>= 1) {
        #pragma unroll
        for (int e = 0; e < E_; ++e) {
            accr[e] += __shfl_down(accr[e], off, 64);
            accn[e] += __shfl_down(accn[e], off, 64);
        }
    }

    if (lane == 0) {
        float rl[E_], p[E_];
        #pragma unroll
        for (int e = 0; e < E_; ++e) {
            const float nx = accn[e] + bn[e];
            // softplus(x) = max(x,0) + log1p(exp(-|x|))  (jax.nn.softplus-stable)
            const float sp = fmaxf(nx, 0.f) + log1pf(expf(-fabsf(nx)));
            rl[e] = accr[e] + br[e] + noise[t * E_ + e] * sp;
        }
        const float m = fmaxf(fmaxf(rl[0], rl[1]), fmaxf(rl[2], rl[3]));
        float s = 0.f;
        #pragma unroll
        for (int e = 0; e < E_; ++e) { p[e] = expf(rl[e] - m); s += p[e]; }
        const float inv = 1.f / s;
        #pragma unroll
        for (int e = 0; e < E_; ++e) p[e] *= inv;

        // route_prob and route_prob_revised (identical), vectorized stores
        const float4 pv = make_float4(p[0], p[1], p[2], p[3]);
        *(float4*)(out + OUT_PROB_OFF + (size_t)t * E_) = pv;
        *(float4*)(out + OUT_PROB_OFF + (size_t)T_ * E_ + (size_t)t * E_) = pv;

        // stable descending sort of 4 (matches argsort(-p) stability)
        float pr[E_]; int id[E_];
        #pragma unroll
        for (int e = 0; e < E_; ++e) { pr[e] = p[e]; id[e] = e; }
        for (int i = 1; i < E_; ++i) {
            const float pv2 = pr[i]; const int iv = id[i];
            int j = i - 1;
            while (j >= 0 && pr[j] < pv2) { pr[j+1] = pr[j]; id[j+1] = id[j]; --j; }
            pr[j+1] = pv2; id[j+1] = iv;
        }
        // mask = cum < 0.5, mask[0] forced true; cum nondecreasing -> prefix count
        float cum = pr[0];
        int k = 1;
        #pragma unroll
        for (int i = 1; i < E_; ++i) { cum += pr[i]; k += (cum < 0.5f) ? 1 : 0; }
        atomicMax(maxk, k);

        *(int4*)(sidx + t * E_)    = make_int4(id[0], id[1], id[2], id[3]);
        *(float4*)(sprob + t * E_) = make_float4(pr[0], pr[1], pr[2], pr[3]);
    }
}

__global__ __launch_bounds__(256) void combine_kernel(
    const float4* __restrict__ logits, const int* __restrict__ maxk,
    const int* __restrict__ sidx, const float* __restrict__ sprob,
    float4* __restrict__ out)
{
    const int t = blockIdx.y;
    const int tid = blockIdx.x * 256 + threadIdx.x;   // [0, 4096)

    __shared__ int k_s;
    __shared__ int id_s[E_];
    __shared__ float w_s[E_];
    if (threadIdx.x == 0) {
        const int k = *maxk;
        k_s = k;
        float pr[E_]; float s = 0.f;
        #pragma unroll
        for (int j = 0; j < E_; ++j) {
            id_s[j] = sidx[t * E_ + j];
            pr[j] = (j < k) ? sprob[t * E_ + j] : 0.f;
            s += pr[j];
        }
        const float inv = 1.f / (s + 1e-6f);
        #pragma unroll
        for (int j = 0; j < E_; ++j) w_s[j] = pr[j] * inv;
    }
    __syncthreads();
    if (tid >= HALF4_) return;

    const int k = k_s;
    const size_t base = (size_t)t * V4_;
    float4 acc0 = {0.f, 0.f, 0.f, 0.f};
    float4 acc1 = {0.f, 0.f, 0.f, 0.f};
    for (int j = 0; j < k; ++j) {          // only max_k experts have nonzero weight
        const float w = w_s[j];
        const size_t eb = (size_t)id_s[j] * EXPERT_STRIDE4 + base;
        const float4 l0 = logits[eb + tid];
        const float4 l1 = logits[eb + tid + HALF4_];
        acc0.x += w * l0.x; acc0.y += w * l0.y; acc0.z += w * l0.z; acc0.w += w * l0.w;
        acc1.x += w * l1.x; acc1.y += w * l1.y; acc1.z += w * l1.z; acc1.w += w * l1.w;
    }
    out[base + tid] = acc0;
    out[base + tid + HALF4_] = acc1;
}

extern "C" void kernel_launch(void* const* d_in, const int* in_sizes, int n_in,
                              void* d_out, int out_size, void* d_ws, size_t ws_size,
                              hipStream_t stream) {
    const float* emb   = (const float*)d_in[0];
    const float* logit = (const float*)d_in[1];
    const float* noise = (const float*)d_in[2];
    const float* Wr    = (const float*)d_in[3];
    const float* br    = (const float*)d_in[4];
    const float* Wn    = (const float*)d_in[5];
    const float* bn    = (const float*)d_in[6];
    float* out = (float*)d_out;

    int*   maxk  = (int*)d_ws;
    int*   sidx  = (int*)((char*)d_ws + 16);
    float* sprob = (float*)((char*)d_ws + 16 + T_ * E_ * sizeof(int));

    init_ws_kernel<<<1, 1, 0, stream>>>(maxk);
    router_kernel<<<T_ / 4, 256, 0, stream>>>(emb, noise, Wr, br, Wn, bn,
                                              out, maxk, sidx, sprob);
    dim3 cgrid(16, T_);   // 16*256 = 4096 threads >= HALF4_=4000 per token
    combine_kernel<<<cgrid, 256, 0, stream>>>((const float4*)logit, maxk,
                                              sidx, sprob, (float4*)d_out);
}